// Round 11
// baseline (117.190 us; speedup 1.0000x reference)
//
#include <hip/hip_runtime.h>
#include <math.h>

// output offsets (floats)
#define O_TZ1      0
#define O_TZ2      1024
#define O_FWD      2048
#define O_EQUI     18432
#define O_ATTN     18433
#define O_ORTH     35841
#define O_PAR      35842
#define O_COMM     35843
#define O_SPARSE   35844
#define O_SECLOSS  35845
#define O_SUB      35846

// partial-slot layout (floats at ws+64) — every slot written unconditionally each launch
#define P_SECLOSS  0      // 64
#define P_SPARSE   64     // 256
#define P_CPAIR    320    // 120  (total 440)

#define S2_BLOCKS  2360u

typedef short s16x8 __attribute__((ext_vector_type(8)));
typedef float f32x4 __attribute__((ext_vector_type(4)));

__device__ __forceinline__ void block_store(float v, float* red, int t, float* slot, float scale)
{
    red[t] = v;
    __syncthreads();
    for (int off = 128; off > 0; off >>= 1) { if (t < off) red[t] += red[t+off]; __syncthreads(); }
    if (t == 0) *slot = red[0] * scale;
}

// block-reduce, atomic-add to acc double, bump arrival counter (ordered after the acc add),
// return true in ALL threads of the last-arriving block.
__device__ __forceinline__ bool block_arrive(float v, float* red, int t, double* dst, float scale,
                                             unsigned int* counter, unsigned int* lf)
{
    red[t] = v;
    __syncthreads();
    for (int off = 128; off > 0; off >>= 1) { if (t < off) red[t] += red[t+off]; __syncthreads(); }
    if (t == 0) {
        double oldv = atomicAdd(dst, (double)(red[0] * scale));
        float dep = (float)oldv;
        __asm__ volatile("" : : "v"(dep));   // consume return value: orders acc-add before counter-bump
        *lf = (atomicAdd(counter, 1u) == S2_BLOCKS - 1u) ? 1u : 0u;
    }
    __syncthreads();
    return *lf != 0u;
}

__device__ __forceinline__ unsigned short f2bf(float x)
{
    unsigned int u = __float_as_uint(x);
    u = (u + 0x7FFFu + ((u >> 16) & 1u)) >> 16;   // RNE
    return (unsigned short)u;
}

// expm via scaling-squaring + Taylor-8; result left in sm[256..511] ("T").
// sm needs >= 784 floats: As 0..255, T 256..511, P 512..767, rowsum 768..783.
__device__ __forceinline__ void expm_core(const float* __restrict__ src, float sign,
                                          float* sm, int* shi, int t)
{
    float* As = sm; float* T = sm + 256; float* P = sm + 512; float* rowsum = sm + 768;
    float a = src[t];
    As[t] = a;
    __syncthreads();
    if (t < 16) {
        float rs = 0.f;
        #pragma unroll
        for (int k = 0; k < 16; ++k) rs += fabsf(As[t*16+k]);
        rowsum[t] = rs;
    }
    __syncthreads();
    if (t == 0) {
        float nrm = 0.f;
        for (int i = 0; i < 16; ++i) nrm = fmaxf(nrm, rowsum[i]);
        int s = 0;
        if (nrm > 0.66f) { s = (int)ceilf(log2f(nrm * 1.51515f)); if (s < 0) s = 0; }
        *shi = s;
    }
    __syncthreads();
    int sq = *shi;
    float scale = sign * exp2f((float)(-sq));
    int i = t >> 4, j = t & 15;
    float as = a * scale;
    As[t] = as;
    T[t]  = ((i==j) ? 1.0f : 0.0f) + as;
    P[t]  = as;
    __syncthreads();
    for (int k = 2; k <= 8; ++k) {
        float accv = 0.f;
        #pragma unroll
        for (int m = 0; m < 16; ++m) accv += P[i*16+m]*As[m*16+j];
        float rk = 1.0f/(float)k;
        __syncthreads();
        float term = accv * rk;
        P[t] = term;
        T[t] += term;
        __syncthreads();
    }
    for (int q = 0; q < sq; ++q) {
        float accv = 0.f;
        #pragma unroll
        for (int m = 0; m < 16; ++m) accv += T[i*16+m]*T[m*16+j];
        __syncthreads();
        T[t] = accv;
        __syncthreads();
    }
}

// MFMA gram core: 128x128 tile of normalized-row gram.
// A[m=lane&15][k=quad*8+j], B[k=quad*8+j][n=lane&15]; k>=16 zero-padded.
// DO_LOG uses the log-product trick: one log2 per 4 entries (min product 1e-36 > FLT_MIN).
template <bool DO_LOG>
__device__ __forceinline__ float gram_mfma(const unsigned short* __restrict__ diffb,
                                           int baseM, int baseN, int t)
{
    int lane = t & 63;
    int wave = t >> 6;
    int quad = lane >> 4;
    int col  = lane & 15;
    const s16x8* pb = (const s16x8*)diffb;   // 2 x s16x8 per row
    s16x8 zf = {0,0,0,0,0,0,0,0};
    s16x8 A0 = zf, A1 = zf;
    s16x8 B0 = zf, B1 = zf, B2 = zf, B3 = zf, B4 = zf, B5 = zf, B6 = zf, B7 = zf;
    if (quad < 2) {
        int q = quad;
        A0 = pb[(baseM + wave*32      + col)*2 + q];
        A1 = pb[(baseM + wave*32 + 16 + col)*2 + q];
        B0 = pb[(baseN +   0 + col)*2 + q];
        B1 = pb[(baseN +  16 + col)*2 + q];
        B2 = pb[(baseN +  32 + col)*2 + q];
        B3 = pb[(baseN +  48 + col)*2 + q];
        B4 = pb[(baseN +  64 + col)*2 + q];
        B5 = pb[(baseN +  80 + col)*2 + q];
        B6 = pb[(baseN +  96 + col)*2 + q];
        B7 = pb[(baseN + 112 + col)*2 + q];
    }
    f32x4 cz = {0.f, 0.f, 0.f, 0.f};
    float accf = 0.f;
#define GTILE(AF, BF) { \
    f32x4 c = __builtin_amdgcn_mfma_f32_16x16x32_bf16(AF, BF, cz, 0, 0, 0); \
    if (DO_LOG) { \
        float p0 = (c[0]*c[0] + 1e-9f) * (c[1]*c[1] + 1e-9f); \
        float p1 = (c[2]*c[2] + 1e-9f) * (c[3]*c[3] + 1e-9f); \
        accf += __log2f(p0 * p1); \
    } else { \
        accf += c[0]*c[0] + c[1]*c[1] + c[2]*c[2] + c[3]*c[3]; \
    } }
    GTILE(A0,B0) GTILE(A0,B1) GTILE(A0,B2) GTILE(A0,B3)
    GTILE(A0,B4) GTILE(A0,B5) GTILE(A0,B6) GTILE(A0,B7)
    GTILE(A1,B0) GTILE(A1,B1) GTILE(A1,B2) GTILE(A1,B3)
    GTILE(A1,B4) GTILE(A1,B5) GTILE(A1,B6) GTILE(A1,B7)
#undef GTILE
    return accf;
}

__device__ __forceinline__ double dsum(const float* __restrict__ p, int n, int t, double* dred)
{
    double local = 0.0;
    for (int i = t; i < n; i += 256) local += (double)p[i];
    dred[t] = local;
    __syncthreads();
    for (int off = 128; off > 0; off >>= 1) { if (t < off) dred[t] += dred[t+off]; __syncthreads(); }
    double r = dred[0];
    __syncthreads();
    return r;
}

// ---------------- K1: [0,64) prob+ssyms | [64,320) expm(ge)+diff+bf16+sparse | [320,440) commut ----------------
__global__ void k_stage1(const float* __restrict__ mean, const float* __restrict__ logvar,
                         const float* __restrict__ latent, const float* __restrict__ ge,
                         const float* __restrict__ lin_w, const float* __restrict__ lin_b,
                         const float* __restrict__ gumbel,
                         float* __restrict__ out, float* __restrict__ S_ws,
                         unsigned short* __restrict__ diffb, float* __restrict__ part,
                         double* __restrict__ acc, unsigned int* __restrict__ counter)
{
    __shared__ float smem[4864];
    __shared__ int shi;
    int bid = blockIdx.x;
    int t = threadIdx.x;

    if (bid == 0 && t == 0) {
        acc[0] = 0.0; acc[1] = 0.0; acc[2] = 0.0;
        *counter = 0u;
    }

    if (bid < 64) {
        int b = bid;
        float* feat = smem;            // 64
        float* probb = smem + 64;      // 288
        float* red16 = smem + 352;     // 16
        float* wrow = smem + 368;      // 256
        if (t < 64) {
            int k = t; float v;
            if (k < 16)       v = mean[b*16 + k];
            else if (k < 32)  v = expf(0.5f * logvar[b*16 + (k-16)]);
            else if (k < 48)  v = mean[(64+b)*16 + (k-32)];
            else              v = expf(0.5f * mean[(64+b)*16 + (k-48)]);
            feat[k] = v;
        }
        __syncthreads();
        for (int j = t; j < 288; j += 256) {
            float a = lin_b[j];
            const float* wr = lin_w + j*64;
            #pragma unroll
            for (int k = 0; k < 64; ++k) a += feat[k]*wr[k];
            probb[j] = a;
        }
        __syncthreads();
        if (t < 16) {
            int s = t;
            float l0 = probb[2*s], l1 = probb[2*s+1];
            float M = fmaxf(l0,l1);
            float e0 = expf(l0-M), e1 = expf(l1-M);
            float Z = e0+e1;
            float p0 = e0/Z, p1 = e1/Z;
            float M2 = fmaxf(p0,p1);
            float lse = M2 + logf(expf(p0-M2)+expf(p1-M2));
            float ls0 = p0 - lse, ls1 = p1 - lse;
            float z1v = latent[b*16+s], z2v = latent[(64+b)*16+s];
            int tt = (fabsf(z1v - z2v) > 0.2f) ? 1 : 0;
            red16[s] = -(tt ? ls1 : ls0);
            int r = b*16 + s;
            float x0 = (l0 + gumbel[2*r])   * 10000.0f;
            float x1 = (l1 + gumbel[2*r+1]) * 10000.0f;
            float Ma = fmaxf(x0,x1);
            float a0 = expf(x0-Ma), a1 = expf(x1-Ma);
            float Za = a0+a1;
            a0 /= Za; a1 /= Za;
            float sw = ((a0 >= 0.5f) || (a1 > 0.5f)) ? a1 : 0.0f;
            out[O_ATTN + b*272 + s] = sw;
            const float* fl = &probb[32 + s*16];
            float mf = fl[0];
            #pragma unroll
            for (int u = 1; u < 16; ++u) mf = fmaxf(mf, fl[u]);
            float ex[16]; float Zf = 0.f;
            #pragma unroll
            for (int u = 0; u < 16; ++u) { ex[u] = expf(fl[u]-mf); Zf += ex[u]; }
            float rZ = 1.0f/Zf;
            #pragma unroll
            for (int u = 0; u < 16; ++u) {
                float fp = ex[u]*rZ;
                out[O_ATTN + b*272 + 16 + s*16 + u] = fp;
                wrow[s*16 + u] = sw*fp;
            }
        }
        __syncthreads();
        if (t == 0) {
            float s = 0.f;
            for (int i = 0; i < 16; ++i) s += red16[i];
            part[P_SECLOSS + b] = s;
        }
        float Stot = 0.f;
        for (int s = 0; s < 16; ++s) {
            float a = 0.f;
            #pragma unroll
            for (int u = 0; u < 16; ++u)
                a += wrow[s*16+u] * ge[(s*16+u)*256 + t];
            out[O_SUB + b*4096 + s*256 + t] = a;
            Stot += a;
        }
        S_ws[b*256 + t] = Stot;
    } else if (bid < 320) {
        // ---- fused expm(ge[e]) + diff + normalize + bf16 + sparse ----
        int e = bid - 64;
        float* zsh = smem + 784;      // 2048
        float* red = smem + 2832;     // 256
        #pragma unroll
        for (int q = 0; q < 8; ++q) zsh[t+256*q] = latent[t+256*q];
        expm_core(ge + e*256, 1.0f, smem, &shi, t);   // T = smem+256; its syncs cover zsh
        const float* T = smem + 256;
        float pv = 0.f;
        if (t < 128) {
            float zr[16];
            #pragma unroll
            for (int k = 0; k < 16; ++k) zr[k] = zsh[t*16+k];
            float dv[16];
            float sum = 0.f, mx = 0.f;
            #pragma unroll
            for (int d = 0; d < 16; ++d) {
                float a = 0.f;
                #pragma unroll
                for (int k = 0; k < 16; ++k) a += zr[k]*T[k*16+d];
                float v = zr[d] - a;
                dv[d] = v;
                float v2 = v*v;
                sum += v2; mx = fmaxf(mx, v2);
            }
            float sm2 = sum - mx;
            pv = sm2*sm2;
            float ri = 1.0f / sqrtf(sum);
            unsigned int pk[8];
            #pragma unroll
            for (int d = 0; d < 8; ++d) {
                unsigned short h0 = f2bf(dv[2*d]   * ri);
                unsigned short h1 = f2bf(dv[2*d+1] * ri);
                pk[d] = (unsigned int)h0 | ((unsigned int)h1 << 16);
            }
            uint4* dst = (uint4*)(diffb + (size_t)(e*128 + t)*16);
            dst[0] = make_uint4(pk[0], pk[1], pk[2], pk[3]);
            dst[1] = make_uint4(pk[4], pk[5], pk[6], pk[7]);
        }
        block_store(pv, red, t, part + P_SPARSE + e, 1.0f);
    } else {
        int idx = bid - 320;
        float* G = smem;             // 4096
        float* gA = smem + 4096;     // 256
        float* gB = smem + 4352;     // 256
        float* red = smem + 4608;    // 256
        int a2 = 0, cnt = 15, rem = idx;
        while (rem >= cnt) { rem -= cnt; a2++; cnt--; }
        int b2 = a2 + 1 + rem;
        #pragma unroll
        for (int q = 0; q < 16; ++q) {
            int ii = t + 256*q;
            int k = ii >> 8, x = ii & 255;
            G[ii] = ge[k*16*256 + x];
        }
        gA[t] = ge[a2*256+t];
        gB[t] = ge[b2*256+t];
        __syncthreads();
        int i = t >> 4, j = t & 15;
        float v1 = 0.f, v2 = 0.f;
        #pragma unroll
        for (int k = 0; k < 16; ++k) {
            v1 += gA[i*16+k]*G[k*256 + b2*16 + j];
            v2 += gB[i*16+k]*G[k*256 + a2*16 + j];
        }
        float d = v1 - v2;
        block_store(d*d, red, t, part + P_CPAIR + idx, 2.0f);
    }
}

// ---------------- K2: [0,64) expm(+-S)+fwd+tz+equi | [64,2240) parallel | [2240,2360) orth ----------------
//                  last-arriving block finalizes all scalar outputs (atomics-only protocol, no fences)
__global__ void __launch_bounds__(256) k_stage2(const float* __restrict__ latent,
                                                const float* __restrict__ S_ws,
                                                const unsigned short* __restrict__ diffb,
                                                const int* __restrict__ sec_idx,
                                                float* __restrict__ out,
                                                float* __restrict__ part,
                                                double* __restrict__ acc,
                                                unsigned int* __restrict__ counter)
{
    __shared__ float smem[1040];   // expm scratch 784 + red 256
    __shared__ double dred[256];
    __shared__ double sacc[3];
    __shared__ int shi;
    __shared__ unsigned int lf;
    int bid = blockIdx.x;
    int t = threadIdx.x;
    float* red = smem + 784;
    bool last;

    if (bid < 64) {
        int b = bid;
        expm_core(S_ws + b*256, 1.0f, smem, &shi, t);
        const float* T = smem + 256;
        out[O_FWD + b*256 + t] = T[t];
        float t1 = 0.f, z1d = 0.f, z2d = 0.f;
        if (t < 16) {
            int d = t;
            #pragma unroll
            for (int k = 0; k < 16; ++k) t1 += latent[b*16+k] * T[k*16+d];
            out[O_TZ1 + b*16 + d] = t1;
            z1d = latent[b*16+d];
            z2d = latent[(64+b)*16+d];
        }
        expm_core(S_ws + b*256, -1.0f, smem, &shi, t);   // internal syncs order prior T reads
        float t2 = 0.f, ep = 0.f;
        if (t < 16) {
            int d = t;
            #pragma unroll
            for (int k = 0; k < 16; ++k) t2 += latent[(64+b)*16+k] * T[k*16+d];
            out[O_TZ2 + b*16 + d] = t2;
            ep = (t2 - z1d)*(t2 - z1d) + (t1 - z2d)*(t1 - z2d);
        }
        last = block_arrive(ep, red, t, &acc[2], 1.0f, counter, &lf);
    } else if (bid < 2240) {
        int tile = bid - 64;
        int s = tile & 15;        // XCD-locality swizzle
        int r = tile >> 4;        // 0..135
        int tm = 0;
        while (r >= 16 - tm) { r -= 16 - tm; tm++; }
        int tn = tm + r;
        float accf = gram_mfma<true>(diffb, s*2048 + tm*128, s*2048 + tn*128, t);
        float wt = (tm == tn) ? 1.0f : 2.0f;
        last = block_arrive(accf, red, t, &acc[0], wt, counter, &lf);
    } else {
        int idx = bid - 2240;
        int sm = 0, cnt = 15, rem = idx;
        while (rem >= cnt) { rem -= cnt; sm++; cnt--; }
        int sn = sm + 1 + rem;
        int em = sm*16 + sec_idx[sm];
        int en = sn*16 + sec_idx[sn];
        float accf = gram_mfma<false>(diffb, em*128, en*128, t);
        last = block_arrive(accf, red, t, &acc[1], 2.0f, counter, &lf);
    }

    if (last) {
        if (t == 0) {
            sacc[0] = atomicAdd(&acc[0], 0.0);   // atomic read: L2-coherent across XCDs
            sacc[1] = atomicAdd(&acc[1], 0.0);
            sacc[2] = atomicAdd(&acc[2], 0.0);
        }
        __syncthreads();
        double s_sec = dsum(part + P_SECLOSS, 64, t, dred);
        double s_spa = dsum(part + P_SPARSE, 256, t, dred);
        double local = 0.0;
        if (t < 120) local = (double)(120 - t) * (double)part[P_CPAIR + t];
        dred[t] = local;
        __syncthreads();
        for (int off = 128; off > 0; off >>= 1) { if (t < off) dred[t] += dred[t+off]; __syncthreads(); }
        if (t == 0) {
            out[O_COMM]    = (float)(dred[0] / 16777216.0);
            out[O_EQUI]    = (float)(sacc[2] / 1024.0);
            out[O_ORTH]    = (float)(sacc[1] / (2048.0*2048.0));
            out[O_PAR]     = (float)(-sacc[0] * 0.6931471805599453 / 67108864.0);
            out[O_SPARSE]  = (float)(s_spa / 32768.0);
            out[O_SECLOSS] = (float)(s_sec / 64.0);
        }
    }
}

extern "C" void kernel_launch(void* const* d_in, const int* in_sizes, int n_in,
                              void* d_out, int out_size, void* d_ws, size_t ws_size,
                              hipStream_t stream)
{
    const float* mean    = (const float*)d_in[0];
    const float* logvar  = (const float*)d_in[1];
    const float* latent  = (const float*)d_in[2];
    const float* ge      = (const float*)d_in[3];
    const float* lin_w   = (const float*)d_in[4];
    const float* lin_b   = (const float*)d_in[5];
    const float* gumbel  = (const float*)d_in[6];
    const int*   sec_idx = (const int*)d_in[7];
    float* out = (float*)d_out;

    char* ws = (char*)d_ws;
    double* acc = (double*)ws;                              // 3 doubles (zeroed by stage1)
    float* part = (float*)(ws + 64);                        // 440 floats (all written each launch)
    unsigned int* counter = (unsigned int*)(ws + 12288);    // zeroed by stage1
    float* S_ws = (float*)(ws + 16384);                     // 16384 floats
    unsigned short* diffb = (unsigned short*)(ws + 81920);  // 32768 rows x 16 bf16 = 1 MB

    k_stage1<<<440,  256, 0, stream>>>(mean, logvar, latent, ge, lin_w, lin_b, gumbel,
                                       out, S_ws, diffb, part, acc, counter);
    k_stage2<<<2360, 256, 0, stream>>>(latent, S_ws, diffb, sec_idx, out, part, acc, counter);
}

// Round 12
// 92.983 us; speedup vs baseline: 1.2603x; 1.2603x over previous
//
#include <hip/hip_runtime.h>
#include <math.h>

// output offsets (floats)
#define O_TZ1      0
#define O_TZ2      1024
#define O_FWD      2048
#define O_EQUI     18432
#define O_ATTN     18433
#define O_ORTH     35841
#define O_PAR      35842
#define O_COMM     35843
#define O_SPARSE   35844
#define O_SECLOSS  35845
#define O_SUB      35846

// partial-slot layout (floats at ws base) — every slot written unconditionally each launch
#define P_SECLOSS  0      // 64
#define P_SPARSE   64     // 256
#define P_CPAIR    320    // 120
#define P_EQUI     440    // 64
#define P_PAR      504    // 2176
#define P_ORTH     2680   // 120  (total 2800)

typedef short s16x8 __attribute__((ext_vector_type(8)));
typedef float f32x4 __attribute__((ext_vector_type(4)));

__device__ __forceinline__ void block_store(float v, float* red, int t, float* slot, float scale)
{
    red[t] = v;
    __syncthreads();
    for (int off = 128; off > 0; off >>= 1) { if (t < off) red[t] += red[t+off]; __syncthreads(); }
    if (t == 0) *slot = red[0] * scale;
}

// single-sync block reduction: wave shuffle + 4-slot LDS combine
__device__ __forceinline__ void block_store2(float v, float* red4, int t, float* slot, float scale)
{
    #pragma unroll
    for (int off = 32; off > 0; off >>= 1) v += __shfl_down(v, off);
    if ((t & 63) == 0) red4[t >> 6] = v;
    __syncthreads();
    if (t == 0) *slot = (red4[0] + red4[1] + red4[2] + red4[3]) * scale;
}

__device__ __forceinline__ unsigned short f2bf(float x)
{
    unsigned int u = __float_as_uint(x);
    u = (u + 0x7FFFu + ((u >> 16) & 1u)) >> 16;   // RNE
    return (unsigned short)u;
}

// expm via scaling-squaring + Taylor-8; result left in sm[256..511] ("T").
// sm needs >= 784 floats: As 0..255, T 256..511, P 512..767, rowsum 768..783.
__device__ __forceinline__ void expm_core(const float* __restrict__ src, float sign,
                                          float* sm, int* shi, int t)
{
    float* As = sm; float* T = sm + 256; float* P = sm + 512; float* rowsum = sm + 768;
    float a = src[t];
    As[t] = a;
    __syncthreads();
    if (t < 16) {
        float rs = 0.f;
        #pragma unroll
        for (int k = 0; k < 16; ++k) rs += fabsf(As[t*16+k]);
        rowsum[t] = rs;
    }
    __syncthreads();
    if (t == 0) {
        float nrm = 0.f;
        for (int i = 0; i < 16; ++i) nrm = fmaxf(nrm, rowsum[i]);
        int s = 0;
        if (nrm > 0.66f) { s = (int)ceilf(log2f(nrm * 1.51515f)); if (s < 0) s = 0; }
        *shi = s;
    }
    __syncthreads();
    int sq = *shi;
    float scale = sign * exp2f((float)(-sq));
    int i = t >> 4, j = t & 15;
    float as = a * scale;
    As[t] = as;
    T[t]  = ((i==j) ? 1.0f : 0.0f) + as;
    P[t]  = as;
    __syncthreads();
    for (int k = 2; k <= 8; ++k) {
        float accv = 0.f;
        #pragma unroll
        for (int m = 0; m < 16; ++m) accv += P[i*16+m]*As[m*16+j];
        float rk = 1.0f/(float)k;
        __syncthreads();
        float term = accv * rk;
        P[t] = term;
        T[t] += term;
        __syncthreads();
    }
    for (int q = 0; q < sq; ++q) {
        float accv = 0.f;
        #pragma unroll
        for (int m = 0; m < 16; ++m) accv += T[i*16+m]*T[m*16+j];
        __syncthreads();
        T[t] = accv;
        __syncthreads();
    }
}

// MFMA gram core with LDS-staged tiles. tiles: 256 rows x 24 shorts (48 B padded,
// <=2-way bank aliasing on b128 reads — free). M rows 0..127, N rows 128..255.
// Even if the compiler rematerializes fragment reads per MFMA (R11 pathology for
// global loads), ds_read is ~12cyc vs ~200 — latency chain collapses.
template <bool DO_LOG>
__device__ __forceinline__ float gram_tile_lds(const unsigned short* __restrict__ diffb,
                                               short* tiles, int baseM, int baseN, int t)
{
    const uint4* gd = (const uint4*)diffb;   // 2 uint4 per 32-B row
    #pragma unroll
    for (int q = 0; q < 2; ++q) {
        int idx = t + 256*q;                 // 0..511
        int row = idx >> 1, half = idx & 1;
        int grow = (row < 128) ? (baseM + row) : (baseN + (row - 128));
        uint4 v = gd[grow*2 + half];
        *(uint4*)(tiles + row*24 + half*8) = v;
    }
    __syncthreads();
    int lane = t & 63, wave = t >> 6, quad = lane >> 4, col = lane & 15;
    s16x8 zf = {0,0,0,0,0,0,0,0};
    s16x8 A0=zf, A1=zf, B0=zf, B1=zf, B2=zf, B3=zf, B4=zf, B5=zf, B6=zf, B7=zf;
    if (quad < 2) {
        const short* tm_ = tiles;
        const short* tn_ = tiles + 128*24;
        A0 = *(const s16x8*)(tm_ + (wave*32      + col)*24 + quad*8);
        A1 = *(const s16x8*)(tm_ + (wave*32 + 16 + col)*24 + quad*8);
        B0 = *(const s16x8*)(tn_ + (  0 + col)*24 + quad*8);
        B1 = *(const s16x8*)(tn_ + ( 16 + col)*24 + quad*8);
        B2 = *(const s16x8*)(tn_ + ( 32 + col)*24 + quad*8);
        B3 = *(const s16x8*)(tn_ + ( 48 + col)*24 + quad*8);
        B4 = *(const s16x8*)(tn_ + ( 64 + col)*24 + quad*8);
        B5 = *(const s16x8*)(tn_ + ( 80 + col)*24 + quad*8);
        B6 = *(const s16x8*)(tn_ + ( 96 + col)*24 + quad*8);
        B7 = *(const s16x8*)(tn_ + (112 + col)*24 + quad*8);
    }
    f32x4 cz = {0.f, 0.f, 0.f, 0.f};
    float accf = 0.f;
#define GTILE(AF, BF) { \
    f32x4 c = __builtin_amdgcn_mfma_f32_16x16x32_bf16(AF, BF, cz, 0, 0, 0); \
    if (DO_LOG) { \
        float p0 = (c[0]*c[0] + 1e-9f) * (c[1]*c[1] + 1e-9f); \
        float p1 = (c[2]*c[2] + 1e-9f) * (c[3]*c[3] + 1e-9f); \
        accf += __log2f(p0 * p1); \
    } else { \
        accf += c[0]*c[0] + c[1]*c[1] + c[2]*c[2] + c[3]*c[3]; \
    } }
    GTILE(A0,B0) GTILE(A0,B1) GTILE(A0,B2) GTILE(A0,B3)
    GTILE(A0,B4) GTILE(A0,B5) GTILE(A0,B6) GTILE(A0,B7)
    GTILE(A1,B0) GTILE(A1,B1) GTILE(A1,B2) GTILE(A1,B3)
    GTILE(A1,B4) GTILE(A1,B5) GTILE(A1,B6) GTILE(A1,B7)
#undef GTILE
    return accf;
}

// ---------------- K1: [0,64) prob+ssyms | [64,320) expm(ge)+diff+bf16+sparse | [320,440) commut ----------------
__global__ void k_stage1(const float* __restrict__ mean, const float* __restrict__ logvar,
                         const float* __restrict__ latent, const float* __restrict__ ge,
                         const float* __restrict__ lin_w, const float* __restrict__ lin_b,
                         const float* __restrict__ gumbel,
                         float* __restrict__ out, float* __restrict__ S_ws,
                         unsigned short* __restrict__ diffb, float* __restrict__ part)
{
    __shared__ float smem[4864];
    __shared__ int shi;
    int bid = blockIdx.x;
    int t = threadIdx.x;

    if (bid < 64) {
        int b = bid;
        float* feat = smem;            // 64
        float* probb = smem + 64;      // 288
        float* red16 = smem + 352;     // 16
        float* wrow = smem + 368;      // 256
        if (t < 64) {
            int k = t; float v;
            if (k < 16)       v = mean[b*16 + k];
            else if (k < 32)  v = expf(0.5f * logvar[b*16 + (k-16)]);
            else if (k < 48)  v = mean[(64+b)*16 + (k-32)];
            else              v = expf(0.5f * mean[(64+b)*16 + (k-48)]);
            feat[k] = v;
        }
        __syncthreads();
        for (int j = t; j < 288; j += 256) {
            float a = lin_b[j];
            const float* wr = lin_w + j*64;
            #pragma unroll
            for (int k = 0; k < 64; ++k) a += feat[k]*wr[k];
            probb[j] = a;
        }
        __syncthreads();
        if (t < 16) {
            int s = t;
            float l0 = probb[2*s], l1 = probb[2*s+1];
            float M = fmaxf(l0,l1);
            float e0 = expf(l0-M), e1 = expf(l1-M);
            float Z = e0+e1;
            float p0 = e0/Z, p1 = e1/Z;
            float M2 = fmaxf(p0,p1);
            float lse = M2 + logf(expf(p0-M2)+expf(p1-M2));
            float ls0 = p0 - lse, ls1 = p1 - lse;
            float z1v = latent[b*16+s], z2v = latent[(64+b)*16+s];
            int tt = (fabsf(z1v - z2v) > 0.2f) ? 1 : 0;
            red16[s] = -(tt ? ls1 : ls0);
            int r = b*16 + s;
            float x0 = (l0 + gumbel[2*r])   * 10000.0f;
            float x1 = (l1 + gumbel[2*r+1]) * 10000.0f;
            float Ma = fmaxf(x0,x1);
            float a0 = expf(x0-Ma), a1 = expf(x1-Ma);
            float Za = a0+a1;
            a0 /= Za; a1 /= Za;
            float sw = ((a0 >= 0.5f) || (a1 > 0.5f)) ? a1 : 0.0f;
            out[O_ATTN + b*272 + s] = sw;
            const float* fl = &probb[32 + s*16];
            float mf = fl[0];
            #pragma unroll
            for (int u = 1; u < 16; ++u) mf = fmaxf(mf, fl[u]);
            float ex[16]; float Zf = 0.f;
            #pragma unroll
            for (int u = 0; u < 16; ++u) { ex[u] = expf(fl[u]-mf); Zf += ex[u]; }
            float rZ = 1.0f/Zf;
            #pragma unroll
            for (int u = 0; u < 16; ++u) {
                float fp = ex[u]*rZ;
                out[O_ATTN + b*272 + 16 + s*16 + u] = fp;
                wrow[s*16 + u] = sw*fp;
            }
        }
        __syncthreads();
        if (t == 0) {
            float s = 0.f;
            for (int i = 0; i < 16; ++i) s += red16[i];
            part[P_SECLOSS + b] = s;
        }
        float Stot = 0.f;
        for (int s = 0; s < 16; ++s) {
            float a = 0.f;
            #pragma unroll
            for (int u = 0; u < 16; ++u)
                a += wrow[s*16+u] * ge[(s*16+u)*256 + t];
            out[O_SUB + b*4096 + s*256 + t] = a;
            Stot += a;
        }
        S_ws[b*256 + t] = Stot;
    } else if (bid < 320) {
        // ---- fused expm(ge[e]) + diff + normalize + bf16 + sparse ----
        int e = bid - 64;
        float* zsh = smem + 784;      // 2048
        float* red = smem + 2832;     // 256
        #pragma unroll
        for (int q = 0; q < 8; ++q) zsh[t+256*q] = latent[t+256*q];
        expm_core(ge + e*256, 1.0f, smem, &shi, t);   // T = smem+256; its syncs cover zsh
        const float* T = smem + 256;
        float pv = 0.f;
        if (t < 128) {
            float zr[16];
            #pragma unroll
            for (int k = 0; k < 16; ++k) zr[k] = zsh[t*16+k];
            float dv[16];
            float sum = 0.f, mx = 0.f;
            #pragma unroll
            for (int d = 0; d < 16; ++d) {
                float a = 0.f;
                #pragma unroll
                for (int k = 0; k < 16; ++k) a += zr[k]*T[k*16+d];
                float v = zr[d] - a;
                dv[d] = v;
                float v2 = v*v;
                sum += v2; mx = fmaxf(mx, v2);
            }
            float sm2 = sum - mx;
            pv = sm2*sm2;
            float ri = 1.0f / sqrtf(sum);
            unsigned int pk[8];
            #pragma unroll
            for (int d = 0; d < 8; ++d) {
                unsigned short h0 = f2bf(dv[2*d]   * ri);
                unsigned short h1 = f2bf(dv[2*d+1] * ri);
                pk[d] = (unsigned int)h0 | ((unsigned int)h1 << 16);
            }
            uint4* dst = (uint4*)(diffb + (size_t)(e*128 + t)*16);
            dst[0] = make_uint4(pk[0], pk[1], pk[2], pk[3]);
            dst[1] = make_uint4(pk[4], pk[5], pk[6], pk[7]);
        }
        block_store(pv, red, t, part + P_SPARSE + e, 1.0f);
    } else {
        int idx = bid - 320;
        float* G = smem;             // 4096
        float* gA = smem + 4096;     // 256
        float* gB = smem + 4352;     // 256
        float* red = smem + 4608;    // 256
        int a2 = 0, cnt = 15, rem = idx;
        while (rem >= cnt) { rem -= cnt; a2++; cnt--; }
        int b2 = a2 + 1 + rem;
        #pragma unroll
        for (int q = 0; q < 16; ++q) {
            int ii = t + 256*q;
            int k = ii >> 8, x = ii & 255;
            G[ii] = ge[k*16*256 + x];
        }
        gA[t] = ge[a2*256+t];
        gB[t] = ge[b2*256+t];
        __syncthreads();
        int i = t >> 4, j = t & 15;
        float v1 = 0.f, v2 = 0.f;
        #pragma unroll
        for (int k = 0; k < 16; ++k) {
            v1 += gA[i*16+k]*G[k*256 + b2*16 + j];
            v2 += gB[i*16+k]*G[k*256 + a2*16 + j];
        }
        float d = v1 - v2;
        block_store(d*d, red, t, part + P_CPAIR + idx, 2.0f);
    }
}

// ---------------- K2: [0,64) expm(+-S)+fwd+tz+equi | [64,2240) parallel | [2240,2360) orth ----------------
__global__ void __launch_bounds__(256) k_stage2(const float* __restrict__ latent,
                                                const float* __restrict__ S_ws,
                                                const unsigned short* __restrict__ diffb,
                                                const int* __restrict__ sec_idx,
                                                float* __restrict__ out,
                                                float* __restrict__ part)
{
    __shared__ float smem[3328];   // gram tiles 256x24 shorts = 3072 floats; expm uses [0,784)
    __shared__ int shi;
    int bid = blockIdx.x;
    int t = threadIdx.x;
    float* red4 = smem + 3072;     // 4 floats used

    if (bid < 64) {
        int b = bid;
        expm_core(S_ws + b*256, 1.0f, smem, &shi, t);
        const float* T = smem + 256;
        out[O_FWD + b*256 + t] = T[t];
        float t1 = 0.f, z1d = 0.f, z2d = 0.f;
        if (t < 16) {
            int d = t;
            #pragma unroll
            for (int k = 0; k < 16; ++k) t1 += latent[b*16+k] * T[k*16+d];
            out[O_TZ1 + b*16 + d] = t1;
            z1d = latent[b*16+d];
            z2d = latent[(64+b)*16+d];
        }
        expm_core(S_ws + b*256, -1.0f, smem, &shi, t);   // internal syncs order prior T reads
        float t2 = 0.f, ep = 0.f;
        if (t < 16) {
            int d = t;
            #pragma unroll
            for (int k = 0; k < 16; ++k) t2 += latent[(64+b)*16+k] * T[k*16+d];
            out[O_TZ2 + b*16 + d] = t2;
            ep = (t2 - z1d)*(t2 - z1d) + (t1 - z2d)*(t1 - z2d);
        }
        block_store2(ep, red4, t, part + P_EQUI + b, 1.0f);
    } else if (bid < 2240) {
        int tile = bid - 64;
        int s = tile & 15;        // XCD-locality swizzle
        int r = tile >> 4;        // 0..135
        int tm = 0;
        while (r >= 16 - tm) { r -= 16 - tm; tm++; }
        int tn = tm + r;
        float accf = gram_tile_lds<true>(diffb, (short*)smem, s*2048 + tm*128, s*2048 + tn*128, t);
        float wt = (tm == tn) ? 1.0f : 2.0f;
        block_store2(accf, red4, t, part + P_PAR + tile, wt);
    } else {
        int idx = bid - 2240;
        int sm = 0, cnt = 15, rem = idx;
        while (rem >= cnt) { rem -= cnt; sm++; cnt--; }
        int sn = sm + 1 + rem;
        int em = sm*16 + sec_idx[sm];
        int en = sn*16 + sec_idx[sn];
        float accf = gram_tile_lds<false>(diffb, (short*)smem, em*128, en*128, t);
        block_store2(accf, red4, t, part + P_ORTH + idx, 2.0f);
    }
}

// ---------------- K3: final scalar assembly (reads prior-dispatch plain stores) ----------------
__global__ void k_final(const float* __restrict__ part, float* __restrict__ out)
{
    __shared__ double dred[256];
    int t = threadIdx.x;

    double local = 0.0;
    for (int i = t; i < 2176; i += 256) local += (double)part[P_PAR + i];
    dred[t] = local;
    __syncthreads();
    for (int off = 128; off > 0; off >>= 1) { if (t < off) dred[t] += dred[t+off]; __syncthreads(); }
    double s_par = dred[0];
    __syncthreads();

    local = 0.0;
    if (t < 120) local += (double)part[P_ORTH + t];
    dred[t] = local;
    __syncthreads();
    for (int off = 128; off > 0; off >>= 1) { if (t < off) dred[t] += dred[t+off]; __syncthreads(); }
    double s_orth = dred[0];
    __syncthreads();

    local = 0.0;
    if (t < 64) local += (double)part[P_EQUI + t];
    dred[t] = local;
    __syncthreads();
    for (int off = 128; off > 0; off >>= 1) { if (t < off) dred[t] += dred[t+off]; __syncthreads(); }
    double s_equi = dred[0];
    __syncthreads();

    local = (t < 64) ? (double)part[P_SECLOSS + t] : 0.0;
    dred[t] = local;
    __syncthreads();
    for (int off = 128; off > 0; off >>= 1) { if (t < off) dred[t] += dred[t+off]; __syncthreads(); }
    double s_sec = dred[0];
    __syncthreads();

    dred[t] = (double)part[P_SPARSE + t];
    __syncthreads();
    for (int off = 128; off > 0; off >>= 1) { if (t < off) dred[t] += dred[t+off]; __syncthreads(); }
    double s_spa = dred[0];
    __syncthreads();

    local = 0.0;
    if (t < 120) local = (double)(120 - t) * (double)part[P_CPAIR + t];
    dred[t] = local;
    __syncthreads();
    for (int off = 128; off > 0; off >>= 1) { if (t < off) dred[t] += dred[t+off]; __syncthreads(); }

    if (t == 0) {
        out[O_COMM]    = (float)(dred[0] / 16777216.0);
        out[O_EQUI]    = (float)(s_equi / 1024.0);
        out[O_ORTH]    = (float)(s_orth / (2048.0*2048.0));
        out[O_PAR]     = (float)(-s_par * 0.6931471805599453 / 67108864.0);
        out[O_SPARSE]  = (float)(s_spa / 32768.0);
        out[O_SECLOSS] = (float)(s_sec / 64.0);
    }
}

extern "C" void kernel_launch(void* const* d_in, const int* in_sizes, int n_in,
                              void* d_out, int out_size, void* d_ws, size_t ws_size,
                              hipStream_t stream)
{
    const float* mean    = (const float*)d_in[0];
    const float* logvar  = (const float*)d_in[1];
    const float* latent  = (const float*)d_in[2];
    const float* ge      = (const float*)d_in[3];
    const float* lin_w   = (const float*)d_in[4];
    const float* lin_b   = (const float*)d_in[5];
    const float* gumbel  = (const float*)d_in[6];
    const int*   sec_idx = (const int*)d_in[7];
    float* out = (float*)d_out;

    char* ws = (char*)d_ws;
    float* part = (float*)ws;                               // 2800 floats (all written each launch)
    float* S_ws = (float*)(ws + 16384);                     // 16384 floats
    unsigned short* diffb = (unsigned short*)(ws + 81920);  // 32768 rows x 16 bf16 = 1 MB

    k_stage1<<<440,  256, 0, stream>>>(mean, logvar, latent, ge, lin_w, lin_b, gumbel,
                                       out, S_ws, diffb, part);
    k_stage2<<<2360, 256, 0, stream>>>(latent, S_ws, diffb, sec_idx, out, part);
    k_final <<<1,    256, 0, stream>>>(part, out);
}